// Round 17
// baseline (46.861 us; speedup 1.0000x reference)
//
#include <hip/hip_runtime.h>

typedef float v2f __attribute__((ext_vector_type(2)));

#define WPB 4   // waves per block
#define NE  4   // batch elements per wave

__device__ __forceinline__ float xorf(float v, int sb) {
  return __int_as_float(__float_as_int(v) ^ sb);
}
__device__ __forceinline__ v2f xor2(v2f v, int sb) {
  return (v2f){xorf(v.x, sb), xorf(v.y, sb)};
}

// ---- VOP3P packed fp32 helpers; accumulating forms in-place (+v) --------
__device__ __forceinline__ void pkfma_ip(v2f a, v2f b, v2f& acc) {
  asm("v_pk_fma_f32 %0, %1, %2, %0" : "+v"(acc) : "v"(a), "v"(b));
}
__device__ __forceinline__ v2f pkmul_bl(v2f c, v2f v) {
  v2f r; asm("v_pk_mul_f32 %0, %1, %2 op_sel:[0,0] op_sel_hi:[0,1]"
             : "=v"(r) : "v"(c), "v"(v)); return r;
}
__device__ __forceinline__ void pkfma_bl(v2f c, v2f v, v2f& acc) {
  asm("v_pk_fma_f32 %0, %1, %2, %0 op_sel:[0,0,0] op_sel_hi:[0,1,1]"
      : "+v"(acc) : "v"(c), "v"(v));
}
__device__ __forceinline__ void pkfma_bl_n(v2f c, v2f v, v2f& acc) {
  asm("v_pk_fma_f32 %0, %1, %2, %0 op_sel:[0,0,0] op_sel_hi:[0,1,1] neg_lo:[1,0,0] neg_hi:[1,0,0]"
      : "+v"(acc) : "v"(c), "v"(v));
}
__device__ __forceinline__ void pkfma_bh_i(v2f c, v2f v, v2f& acc) {
  asm("v_pk_fma_f32 %0, %1, %2, %0 op_sel:[1,1,0] op_sel_hi:[1,0,1] neg_lo:[1,0,0]"
      : "+v"(acc) : "v"(c), "v"(v));
}
__device__ __forceinline__ void pkfma_bh_mi(v2f c, v2f v, v2f& acc) {
  asm("v_pk_fma_f32 %0, %1, %2, %0 op_sel:[1,1,0] op_sel_hi:[1,0,1] neg_hi:[1,0,0]"
      : "+v"(acc) : "v"(c), "v"(v));
}
__device__ __forceinline__ v2f cmul(v2f a, v2f b) {
  v2f r = pkmul_bl(a, b);
  pkfma_bh_i(a, b, r);
  return r;
}

// ---- cross-lane exchange ------------------------------------------------
__device__ __forceinline__ v2f bperm2(int addr, v2f v) {
  v2f r;
  r.x = __int_as_float(__builtin_amdgcn_ds_bpermute(addr, __float_as_int(v.x)));
  r.y = __int_as_float(__builtin_amdgcn_ds_bpermute(addr, __float_as_int(v.y)));
  return r;
}
// compile-time-mask exchange (readout only; body is single-instance)
template<int M>
__device__ __forceinline__ float xch(float v, int a32) {
  if constexpr (M == 32)
    return __int_as_float(__builtin_amdgcn_ds_bpermute(a32, __float_as_int(v)));
  else if constexpr (M == 16 || M == 4)
    return __int_as_float(__builtin_amdgcn_ds_swizzle(__float_as_int(v), (M << 10) | 0x1f));
  else if constexpr (M == 8) {
    int i = __float_as_int(v);
    return __int_as_float(__builtin_amdgcn_update_dpp(i, i, 0x128, 0xF, 0xF, false));
  } else if constexpr (M == 2) {
    int i = __float_as_int(v);
    return __int_as_float(__builtin_amdgcn_update_dpp(i, i, 0x4E, 0xF, 0xF, false));
  } else {
    int i = __float_as_int(v);
    return __int_as_float(__builtin_amdgcn_update_dpp(i, i, 0xB1, 0xF, 0xF, false));
  }
}
template<int M>
__device__ __forceinline__ v2f xch2(v2f v, int a32) {
  v2f r; r.x = xch<M>(v.x, a32); r.y = xch<M>(v.y, a32); return r;
}

// ---- gate cores (R7-verified) -------------------------------------------
__device__ __forceinline__ void gpair(v2f& a, v2f& b, v2f P1, v2f P2) {
  v2f na = pkmul_bl(P1, a);
  pkfma_bh_i(P1, a, na);
  pkfma_bl(P2, b, na);
  pkfma_bh_i(P2, b, na);
  v2f nb = pkmul_bl(P1, b);
  pkfma_bh_mi(P1, b, nb);
  pkfma_bl_n(P2, a, nb);
  pkfma_bh_i(P2, a, nb);
  a = na; b = nb;
}
__device__ __forceinline__ v2f glane(v2f a, v2f p, v2f P1, v2f P2) {
  v2f t = pkmul_bl(P1, a);
  pkfma_bh_i(P1, a, t);
  pkfma_bl(P2, p, t);
  pkfma_bh_i(P2, p, t);
  return t;
}

// product-state build (init + layer-0 Rot folded) into named regs
__device__ __forceinline__ void build_state(v2f& S0, v2f& S1, v2f& S2, v2f& S3,
                                            const float4* csW, int lane) {
  v2f g2, g3, g4, g5, g6, g7;
  #define BG(q, dst) { float4 c = csW[q]; \
    v2f P1 = (v2f){c.x, c.y}; v2f nc2 = (v2f){-c.z, c.w}; \
    dst = (((lane >> (7 - (q))) & 1) != 0) ? nc2 : P1; }
  BG(2, g2) BG(3, g3) BG(4, g4) BG(5, g5) BG(6, g6) BG(7, g7)
  #undef BG
  v2f common = cmul(cmul(cmul(g2, g3), cmul(g4, g5)), cmul(g6, g7));
  float4 c0 = csW[0], c1 = csW[1];
  v2f P10 = (v2f){c0.x, c0.y}, m0 = (v2f){-c0.z, c0.w};
  v2f P11 = (v2f){c1.x, c1.y}, m1 = (v2f){-c1.z, c1.w};
  S0 = cmul(cmul(P10, P11), common);
  S1 = cmul(cmul(P10, m1 ), common);
  S2 = cmul(cmul(m0 , P11), common);
  S3 = cmul(cmul(m0 , m1 ), common);
}

__device__ __forceinline__ void cnot_ring(v2f& S0, v2f& S1, v2f& S2, v2f& S3,
                                          int addrA, int addrB, int lane) {
  { v2f t = S2; S2 = S3; S3 = t; }
  v2f q0 = bperm2(addrA, S0), q2 = bperm2(addrA, S2);
  v2f q1 = bperm2(addrB, S1), q3 = bperm2(addrB, S3);
  bool c0 = (lane & 1) != 0;
  S0 = c0 ? q2 : q0; S2 = c0 ? q0 : q2;
  S1 = c0 ? q3 : q1; S3 = c0 ? q1 : q3;
}

__device__ __forceinline__ float fast_tanh(float x) {
  float e = __expf(2.f * x);
  return 1.f - 2.f * __builtin_amdgcn_rcpf(e + 1.f);
}
__device__ __forceinline__ v2f vlo(float4 v) { return (v2f){v.x, v.y}; }
__device__ __forceinline__ v2f vhi(float4 v) { return (v2f){v.z, v.w}; }

__global__ void prep_rot_kernel(const float* __restrict__ qw, float* __restrict__ U) {
  int t = threadIdx.x;
  if (t < 24) {
    float phi = qw[t*3+0], theta = qw[t*3+1], omega = qw[t*3+2];
    float st, ct; sincosf(0.5f*theta, &st, &ct);
    float sa, ca; sincosf(0.5f*(phi+omega), &sa, &ca);
    float sd, cd; sincosf(0.5f*(phi-omega), &sd, &cd);
    float4 o; o.x = ct*ca; o.y = -ct*sa; o.z = -st*cd; o.w = -st*sd;
    ((float4*)U)[t] = o;
  }
}

__global__ __launch_bounds__(64*WPB, 4) void qblock_kernel(
    const float* __restrict__ x,  const float* __restrict__ W1, const float* __restrict__ b1,
    const float* __restrict__ W2, const float* __restrict__ b2,
    const float* __restrict__ W3, const float* __restrict__ b3,
    const float* __restrict__ Urot, const float* __restrict__ Wp, const float* __restrict__ bp,
    float* __restrict__ out, int B4)
{
  __shared__ float  h1s[WPB][NE][64];
  __shared__ float  h2s[WPB][NE][32];
  __shared__ v2f    cs [WPB][NE][16];
  __shared__ float4 csW[WPB][NE][8];

  const int lane = threadIdx.x & 63;
  const int wv   = threadIdx.x >> 6;
  int bw = blockIdx.x * WPB + wv;
  if (bw >= B4) bw = B4 - 1;
  bw = __builtin_amdgcn_readfirstlane(bw);
  const int e0 = NE * bw;
  const v2f* Ug2 = (const v2f*)Urot;

  // ---- MLP layer 1: 80 -> 64 for 4 elements ----
  {
    const float4* wr = (const float4*)(W1 + lane * 80);
    float bv = b1[lane];
    v2f a0A = (v2f){bv,0.f}, a1A = (v2f){0.f,0.f};
    v2f a0B = a0A, a1B = a1A, a0C = a0A, a1C = a1A, a0D = a0A, a1D = a1A;
    #pragma unroll 4
    for (int k = 0; k < 20; ++k) {
      float4 wk = wr[k];
      #define L1E(E, e) { \
        float4 xk = ((const float4*)(x + (size_t)(e0 + (e)) * 80))[k]; \
        pkfma_ip(vlo(xk), vlo(wk), a0##E); pkfma_ip(vhi(xk), vhi(wk), a1##E); }
      L1E(A,0) L1E(B,1) L1E(C,2) L1E(D,3)
      #undef L1E
    }
    h1s[wv][0][lane] = fast_tanh((a0A.x + a0A.y) + (a1A.x + a1A.y));
    h1s[wv][1][lane] = fast_tanh((a0B.x + a0B.y) + (a1B.x + a1B.y));
    h1s[wv][2][lane] = fast_tanh((a0C.x + a0C.y) + (a1C.x + a1C.y));
    h1s[wv][3][lane] = fast_tanh((a0D.x + a0D.y) + (a1D.x + a1D.y));
  }
  __threadfence_block();

  // ---- layer 2: 64 -> 32; 2 elems per lane ----
  {
    const int ep = lane >> 5, row = lane & 31;
    const float4* wr = (const float4*)(W2 + row * 64);
    const float4* hvA = (const float4*)(&h1s[wv][2*ep+0][0]);
    const float4* hvB = (const float4*)(&h1s[wv][2*ep+1][0]);
    v2f aA0 = (v2f){b2[row], 0.f}, aA1 = (v2f){0.f, 0.f};
    v2f aB0 = aA0, aB1 = aA1;
    #pragma unroll 4
    for (int k = 0; k < 16; ++k) {
      float4 wk = wr[k], hA = hvA[k], hB = hvB[k];
      pkfma_ip(vlo(hA), vlo(wk), aA0); pkfma_ip(vhi(hA), vhi(wk), aA1);
      pkfma_ip(vlo(hB), vlo(wk), aB0); pkfma_ip(vhi(hB), vhi(wk), aB1);
    }
    h2s[wv][2*ep+0][row] = fast_tanh((aA0.x + aA0.y) + (aA1.x + aA1.y));
    h2s[wv][2*ep+1][row] = fast_tanh((aB0.x + aB0.y) + (aB1.x + aB1.y));
  }
  __threadfence_block();

  // ---- layer 3: 32 -> 16 angles; all 64 lanes ----
  {
    const int e = lane >> 4, row = lane & 15;
    const float4* hv = (const float4*)(&h2s[wv][e][0]);
    const float4* wr = (const float4*)(W3 + row * 32);
    v2f ac0 = (v2f){b3[row], 0.f}, ac1 = (v2f){0.f, 0.f};
    #pragma unroll 4
    for (int k = 0; k < 8; ++k) {
      float4 hk = hv[k], wk = wr[k];
      pkfma_ip(vlo(hk), vlo(wk), ac0);
      pkfma_ip(vhi(hk), vhi(wk), ac1);
    }
    float sh, ch; __sincosf(0.5f * ((ac0.x + ac0.y) + (ac1.x + ac1.y)), &sh, &ch);
    cs[wv][e][row] = (v2f){ch, sh};
  }
  __threadfence_block();

  // ---- combine W_i = Rot_l0_i . (RZ_i . RY_i) ----
  if (lane < 32) {
    const int e = lane >> 3, k = lane & 7;
    v2f yy = cs[wv][e][k], zz = cs[wv][e][k + 8];
    v2f u1 = (v2f){  yy.x * zz.x, -yy.x * zz.y };
    v2f u2 = (v2f){ -yy.y * zz.x,  yy.y * zz.y };
    v2f cu1 = (v2f){ u1.x, -u1.y };
    v2f cu2 = (v2f){ u2.x, -u2.y };
    v2f r1 = Ug2[2 * k], r2 = Ug2[2 * k + 1];
    v2f P1c = cmul(r1, u1);
    pkfma_bl_n(r2, cu2, P1c);
    pkfma_bh_mi(r2, cu2, P1c);
    v2f P2c = cmul(r1, u2);
    pkfma_bl(r2, cu1, P2c);
    pkfma_bh_i(r2, cu1, P2c);
    csW[wv][e][k] = make_float4(P1c.x, P1c.y, P2c.x, P2c.y);
  }
  __threadfence_block();

  // ---- per-lane constants ----
  const int a32 = (lane ^ 32) << 2;
  const int sb[6] = { (lane&32)<<26, (lane&16)<<27, (lane&8)<<28,
                      (lane&4)<<29, (lane&2)<<30, (lane&1)<<31 };
  const int addrA = ((lane ^ (lane >> 1)) & 63) << 2;
  const int addrB = addrA ^ 128;

  v2f sA0, sA1, sA2, sA3, sB0, sB1, sB2, sB3;
  v2f sC0, sC1, sC2, sC3, sD0, sD1, sD2, sD3;
  build_state(sA0, sA1, sA2, sA3, &csW[wv][0][0], lane);
  build_state(sB0, sB1, sB2, sB3, &csW[wv][1][0], lane);
  build_state(sC0, sC1, sC2, sC3, &csW[wv][2][0], lane);
  build_state(sD0, sD1, sD2, sD3, &csW[wv][3][0], lane);

  // ---- circuit: LOOPED layers + LOOPED lane-wires (code-size-first) ----
  #pragma unroll 1
  for (int l = 1; l <= 2; ++l) {
    cnot_ring(sA0, sA1, sA2, sA3, addrA, addrB, lane);
    cnot_ring(sB0, sB1, sB2, sB3, addrA, addrB, lane);
    cnot_ring(sC0, sC1, sC2, sC3, addrA, addrB, lane);
    cnot_ring(sD0, sD1, sD2, sD3, addrA, addrB, lane);
    {
      v2f P1 = Ug2[(l*8+0)*2], P2 = Ug2[(l*8+0)*2+1];
      gpair(sA0, sA2, P1, P2); gpair(sA1, sA3, P1, P2);
      gpair(sB0, sB2, P1, P2); gpair(sB1, sB3, P1, P2);
      gpair(sC0, sC2, P1, P2); gpair(sC1, sC3, P1, P2);
      gpair(sD0, sD2, P1, P2); gpair(sD1, sD3, P1, P2);
    }
    {
      v2f P1 = Ug2[(l*8+1)*2], P2 = Ug2[(l*8+1)*2+1];
      gpair(sA0, sA1, P1, P2); gpair(sA2, sA3, P1, P2);
      gpair(sB0, sB1, P1, P2); gpair(sB2, sB3, P1, P2);
      gpair(sC0, sC1, P1, P2); gpair(sC2, sC3, P1, P2);
      gpair(sD0, sD1, P1, P2); gpair(sD2, sD3, P1, P2);
    }
    #pragma unroll 1
    for (int w = 2; w < 8; ++w) {
      const int m = 1 << (7 - w);
      const int am = ((lane ^ m) & 63) << 2;        // bpermute addr for any mask
      const int sw = (lane & m) ? 0x80000000 : 0;   // hi-lane conj sign
      v2f P1 = Ug2[(l*8+w)*2], P2 = Ug2[(l*8+w)*2+1];
      P1.y = xorf(P1.y, sw); P2.x = xorf(P2.x, sw);
      v2f p;
      p = bperm2(am, sA0); sA0 = glane(sA0, p, P1, P2);
      p = bperm2(am, sA1); sA1 = glane(sA1, p, P1, P2);
      p = bperm2(am, sA2); sA2 = glane(sA2, p, P1, P2);
      p = bperm2(am, sA3); sA3 = glane(sA3, p, P1, P2);
      p = bperm2(am, sB0); sB0 = glane(sB0, p, P1, P2);
      p = bperm2(am, sB1); sB1 = glane(sB1, p, P1, P2);
      p = bperm2(am, sB2); sB2 = glane(sB2, p, P1, P2);
      p = bperm2(am, sB3); sB3 = glane(sB3, p, P1, P2);
      p = bperm2(am, sC0); sC0 = glane(sC0, p, P1, P2);
      p = bperm2(am, sC1); sC1 = glane(sC1, p, P1, P2);
      p = bperm2(am, sC2); sC2 = glane(sC2, p, P1, P2);
      p = bperm2(am, sC3); sC3 = glane(sC3, p, P1, P2);
      p = bperm2(am, sD0); sD0 = glane(sD0, p, P1, P2);
      p = bperm2(am, sD1); sD1 = glane(sD1, p, P1, P2);
      p = bperm2(am, sD2); sD2 = glane(sD2, p, P1, P2);
      p = bperm2(am, sD3); sD3 = glane(sD3, p, P1, P2);
    }
  }

  // ---- interleaved readout (pair-groups u=(A,B), w=(C,D)) ----
  v2f zu0,zu1,zu2,zu3,zu4,zu5,zu6,zu7;
  v2f zw0,zw1,zw2,zw3,zw4,zw5,zw6,zw7;
  {
    v2f pu0 = (v2f){fmaf(sA0.x,sA0.x,sA0.y*sA0.y), fmaf(sB0.x,sB0.x,sB0.y*sB0.y)};
    v2f pu1 = (v2f){fmaf(sA1.x,sA1.x,sA1.y*sA1.y), fmaf(sB1.x,sB1.x,sB1.y*sB1.y)};
    v2f pu2 = (v2f){fmaf(sA2.x,sA2.x,sA2.y*sA2.y), fmaf(sB2.x,sB2.x,sB2.y*sB2.y)};
    v2f pu3 = (v2f){fmaf(sA3.x,sA3.x,sA3.y*sA3.y), fmaf(sB3.x,sB3.x,sB3.y*sB3.y)};
    v2f pw0 = (v2f){fmaf(sC0.x,sC0.x,sC0.y*sC0.y), fmaf(sD0.x,sD0.x,sD0.y*sD0.y)};
    v2f pw1 = (v2f){fmaf(sC1.x,sC1.x,sC1.y*sC1.y), fmaf(sD1.x,sD1.x,sD1.y*sD1.y)};
    v2f pw2 = (v2f){fmaf(sC2.x,sC2.x,sC2.y*sC2.y), fmaf(sD2.x,sD2.x,sD2.y*sD2.y)};
    v2f pw3 = (v2f){fmaf(sC3.x,sC3.x,sC3.y*sC3.y), fmaf(sD3.x,sD3.x,sD3.y*sD3.y)};
    v2f Eu = (pu0 + pu3) - (pu1 + pu2), Fu = (pu0 + pu2) - (pu1 + pu3);
    v2f Ew = (pw0 + pw3) - (pw1 + pw2), Fw = (pw0 + pw2) - (pw1 + pw3);
    const int pl = (__popc(lane) & 1) << 31;
    v2f Fvu = xor2(Fu, pl), Fvw = xor2(Fw, pl);
    v2f Smu = Eu, Smw = Ew;
    v2f d1u, d2u, d3u, d4u, d5u, d6u, d1w, d2w, d3w, d4w, d5w, d6w;
    { v2f pu = xch2<32>(Smu, a32); v2f pw = xch2<32>(Smw, a32);
      d1u = xor2(Smu - pu, sb[0]); Smu += pu;
      d1w = xor2(Smw - pw, sb[0]); Smw += pw; }
    { v2f pu = xch2<16>(Smu, a32), qu = xch2<16>(d1u, a32);
      v2f pw = xch2<16>(Smw, a32), qw = xch2<16>(d1w, a32);
      Smu += pu; d2u = xor2(d1u - qu, sb[1]); d1u += qu;
      Smw += pw; d2w = xor2(d1w - qw, sb[1]); d1w += qw; }
    { v2f pu = xch2<8>(Smu, a32), qu = xch2<8>(d1u, a32), ru = xch2<8>(d2u, a32);
      v2f pw = xch2<8>(Smw, a32), qw = xch2<8>(d1w, a32), rw = xch2<8>(d2w, a32);
      Smu += pu; d1u += qu; d3u = xor2(d2u - ru, sb[2]); d2u += ru;
      Smw += pw; d1w += qw; d3w = xor2(d2w - rw, sb[2]); d2w += rw; }
    { v2f pu = xch2<4>(Smu, a32), qu = xch2<4>(d1u, a32),
          ru = xch2<4>(d2u, a32), tu = xch2<4>(d3u, a32);
      v2f pw = xch2<4>(Smw, a32), qw = xch2<4>(d1w, a32),
          rw = xch2<4>(d2w, a32), tw = xch2<4>(d3w, a32);
      Smu += pu; d1u += qu; d2u += ru; d4u = xor2(d3u - tu, sb[3]); d3u += tu;
      Smw += pw; d1w += qw; d2w += rw; d4w = xor2(d3w - tw, sb[3]); d3w += tw; }
    { v2f pu = xch2<2>(Smu, a32), qu = xch2<2>(d1u, a32), ru = xch2<2>(d2u, a32),
          tu = xch2<2>(d3u, a32), wu = xch2<2>(d4u, a32);
      v2f pw = xch2<2>(Smw, a32), qw = xch2<2>(d1w, a32), rw = xch2<2>(d2w, a32),
          tw = xch2<2>(d3w, a32), ww = xch2<2>(d4w, a32);
      Smu += pu; d1u += qu; d2u += ru; d3u += tu;
      d5u = xor2(d4u - wu, sb[4]); d4u += wu;
      Smw += pw; d1w += qw; d2w += rw; d3w += tw;
      d5w = xor2(d4w - ww, sb[4]); d4w += ww; }
    { v2f pu = xch2<1>(Smu, a32), qu = xch2<1>(d1u, a32), ru = xch2<1>(d2u, a32),
          tu = xch2<1>(d3u, a32), wu = xch2<1>(d4u, a32), vu = xch2<1>(d5u, a32);
      v2f pw = xch2<1>(Smw, a32), qw = xch2<1>(d1w, a32), rw = xch2<1>(d2w, a32),
          tw = xch2<1>(d3w, a32), ww = xch2<1>(d4w, a32), vw = xch2<1>(d5w, a32);
      Smu += pu; d1u += qu; d2u += ru; d3u += tu; d4u += wu;
      d6u = xor2(d5u - vu, sb[5]); d5u += vu;
      Smw += pw; d1w += qw; d2w += rw; d3w += tw; d4w += ww;
      d6w = xor2(d5w - vw, sb[5]); d5w += vw; }
    Fvu += xch2<32>(Fvu, a32); Fvw += xch2<32>(Fvw, a32);
    Fvu += xch2<16>(Fvu, a32); Fvw += xch2<16>(Fvw, a32);
    Fvu += xch2<8>(Fvu, a32);  Fvw += xch2<8>(Fvw, a32);
    Fvu += xch2<4>(Fvu, a32);  Fvw += xch2<4>(Fvw, a32);
    Fvu += xch2<2>(Fvu, a32);  Fvw += xch2<2>(Fvw, a32);
    Fvu += xch2<1>(Fvu, a32);  Fvw += xch2<1>(Fvw, a32);
    zu0 = Fvu; zu1 = Smu; zu2 = d1u; zu3 = d2u;
    zu4 = d3u; zu5 = d4u; zu6 = d5u; zu7 = d6u;
    zw0 = Fvw; zw1 = Smw; zw2 = d1w; zw3 = d2w;
    zw4 = d3w; zw5 = d4w; zw6 = d5w; zw7 = d6w;
  }

  // ---- packed projection + stores ----
  const int r0 = 2 * lane;
  const float4* wp = (const float4*)(Wp + r0 * 8);
  float4 w0v = wp[0], w1v = wp[1], w2v = wp[2], w3v = wp[3];
  float2 bpv = ((const float2*)bp)[lane];
  #define PROJ_STORE(P, eA, eB) { \
    v2f o0 = (v2f){bpv.x, bpv.x}; \
    v2f o1 = (v2f){bpv.y, bpv.y}; \
    o0 += z##P##0*w0v.x + z##P##1*w0v.y + z##P##2*w0v.z + z##P##3*w0v.w \
        + z##P##4*w1v.x + z##P##5*w1v.y + z##P##6*w1v.z + z##P##7*w1v.w; \
    o1 += z##P##0*w2v.x + z##P##1*w2v.y + z##P##2*w2v.z + z##P##3*w2v.w \
        + z##P##4*w3v.x + z##P##5*w3v.y + z##P##6*w3v.z + z##P##7*w3v.w; \
    ((float2*)(out + (size_t)(e0 + (eA)) * 128))[lane] = make_float2(o0.x, o1.x); \
    ((float2*)(out + (size_t)(e0 + (eB)) * 128))[lane] = make_float2(o0.y, o1.y); }
  PROJ_STORE(u, 0, 1)
  PROJ_STORE(w, 2, 3)
  #undef PROJ_STORE
}

extern "C" void kernel_launch(void* const* d_in, const int* in_sizes, int n_in,
                              void* d_out, int out_size, void* d_ws, size_t ws_size,
                              hipStream_t stream) {
  const float* x  = (const float*)d_in[0];
  const float* W1 = (const float*)d_in[1];
  const float* b1 = (const float*)d_in[2];
  const float* W2 = (const float*)d_in[3];
  const float* b2 = (const float*)d_in[4];
  const float* W3 = (const float*)d_in[5];
  const float* b3 = (const float*)d_in[6];
  const float* qw = (const float*)d_in[7];
  const float* Wp = (const float*)d_in[8];
  const float* bp = (const float*)d_in[9];
  float* out = (float*)d_out;
  float* Urot = (float*)d_ws;

  const int B = in_sizes[0] / 80;
  const int B4 = B / NE;
  prep_rot_kernel<<<1, 64, 0, stream>>>(qw, Urot);
  const int grid = (B4 + WPB - 1) / WPB;
  qblock_kernel<<<grid, 64 * WPB, 0, stream>>>(x, W1, b1, W2, b2, W3, b3,
                                               Urot, Wp, bp, out, B4);
}

// Round 18
// 39.982 us; speedup vs baseline: 1.1720x; 1.1720x over previous
//
#include <hip/hip_runtime.h>

typedef float v2f __attribute__((ext_vector_type(2)));

#define WPB 4   // waves per block
#define NE  4   // batch elements per wave

__device__ __forceinline__ float xorf(float v, int sb) {
  return __int_as_float(__float_as_int(v) ^ sb);
}
__device__ __forceinline__ v2f xor2(v2f v, int sb) {
  return (v2f){xorf(v.x, sb), xorf(v.y, sb)};
}

// ---- VOP3P packed fp32 helpers; accumulating forms in-place (+v) --------
__device__ __forceinline__ void pkfma_ip(v2f a, v2f b, v2f& acc) {
  asm("v_pk_fma_f32 %0, %1, %2, %0" : "+v"(acc) : "v"(a), "v"(b));
}
__device__ __forceinline__ v2f pkmul_bl(v2f c, v2f v) {
  v2f r; asm("v_pk_mul_f32 %0, %1, %2 op_sel:[0,0] op_sel_hi:[0,1]"
             : "=v"(r) : "v"(c), "v"(v)); return r;
}
__device__ __forceinline__ void pkfma_bl(v2f c, v2f v, v2f& acc) {
  asm("v_pk_fma_f32 %0, %1, %2, %0 op_sel:[0,0,0] op_sel_hi:[0,1,1]"
      : "+v"(acc) : "v"(c), "v"(v));
}
__device__ __forceinline__ void pkfma_bl_n(v2f c, v2f v, v2f& acc) {
  asm("v_pk_fma_f32 %0, %1, %2, %0 op_sel:[0,0,0] op_sel_hi:[0,1,1] neg_lo:[1,0,0] neg_hi:[1,0,0]"
      : "+v"(acc) : "v"(c), "v"(v));
}
__device__ __forceinline__ void pkfma_bh_i(v2f c, v2f v, v2f& acc) {
  asm("v_pk_fma_f32 %0, %1, %2, %0 op_sel:[1,1,0] op_sel_hi:[1,0,1] neg_lo:[1,0,0]"
      : "+v"(acc) : "v"(c), "v"(v));
}
__device__ __forceinline__ void pkfma_bh_mi(v2f c, v2f v, v2f& acc) {
  asm("v_pk_fma_f32 %0, %1, %2, %0 op_sel:[1,1,0] op_sel_hi:[1,0,1] neg_hi:[1,0,0]"
      : "+v"(acc) : "v"(c), "v"(v));
}
__device__ __forceinline__ v2f cmul(v2f a, v2f b) {
  v2f r = pkmul_bl(a, b);
  pkfma_bh_i(a, b, r);
  return r;
}

// ---- cross-lane xor exchange (R6-verified prims) ------------------------
template<int M>
__device__ __forceinline__ float xch(float v, int a32) {
  if constexpr (M == 32)
    return __int_as_float(__builtin_amdgcn_ds_bpermute(a32, __float_as_int(v)));
  else if constexpr (M == 16 || M == 4)
    return __int_as_float(__builtin_amdgcn_ds_swizzle(__float_as_int(v), (M << 10) | 0x1f));
  else if constexpr (M == 8) {
    int i = __float_as_int(v);
    return __int_as_float(__builtin_amdgcn_update_dpp(i, i, 0x128, 0xF, 0xF, false));
  } else if constexpr (M == 2) {
    int i = __float_as_int(v);
    return __int_as_float(__builtin_amdgcn_update_dpp(i, i, 0x4E, 0xF, 0xF, false));
  } else {
    int i = __float_as_int(v);
    return __int_as_float(__builtin_amdgcn_update_dpp(i, i, 0xB1, 0xF, 0xF, false));
  }
}
template<int M>
__device__ __forceinline__ v2f xch2(v2f v, int a32) {
  v2f r; r.x = xch<M>(v.x, a32); r.y = xch<M>(v.y, a32); return r;
}
__device__ __forceinline__ v2f bperm2(int addr, v2f v) {
  v2f r;
  r.x = __int_as_float(__builtin_amdgcn_ds_bpermute(addr, __float_as_int(v.x)));
  r.y = __int_as_float(__builtin_amdgcn_ds_bpermute(addr, __float_as_int(v.y)));
  return r;
}

// ---- gate cores (R7-verified) -------------------------------------------
__device__ __forceinline__ void gpair(v2f& a, v2f& b, v2f P1, v2f P2) {
  v2f na = pkmul_bl(P1, a);
  pkfma_bh_i(P1, a, na);
  pkfma_bl(P2, b, na);
  pkfma_bh_i(P2, b, na);
  v2f nb = pkmul_bl(P1, b);
  pkfma_bh_mi(P1, b, nb);
  pkfma_bl_n(P2, a, nb);
  pkfma_bh_i(P2, a, nb);
  a = na; b = nb;
}
__device__ __forceinline__ v2f glane(v2f a, v2f p, v2f P1, v2f P2) {
  v2f t = pkmul_bl(P1, a);
  pkfma_bh_i(P1, a, t);
  pkfma_bl(P2, p, t);
  pkfma_bh_i(P2, p, t);
  return t;
}

// product-state build (init + layer-0 Rot folded) into named regs
__device__ __forceinline__ void build_state(v2f& S0, v2f& S1, v2f& S2, v2f& S3,
                                            const float4* csW, int lane) {
  v2f g2, g3, g4, g5, g6, g7;
  #define BG(q, dst) { float4 c = csW[q]; \
    v2f P1 = (v2f){c.x, c.y}; v2f nc2 = (v2f){-c.z, c.w}; \
    dst = (((lane >> (7 - (q))) & 1) != 0) ? nc2 : P1; }
  BG(2, g2) BG(3, g3) BG(4, g4) BG(5, g5) BG(6, g6) BG(7, g7)
  #undef BG
  v2f common = cmul(cmul(cmul(g2, g3), cmul(g4, g5)), cmul(g6, g7));
  float4 c0 = csW[0], c1 = csW[1];
  v2f P10 = (v2f){c0.x, c0.y}, m0 = (v2f){-c0.z, c0.w};
  v2f P11 = (v2f){c1.x, c1.y}, m1 = (v2f){-c1.z, c1.w};
  S0 = cmul(cmul(P10, P11), common);
  S1 = cmul(cmul(P10, m1 ), common);
  S2 = cmul(cmul(m0 , P11), common);
  S3 = cmul(cmul(m0 , m1 ), common);
}

__device__ __forceinline__ float fast_tanh(float x) {
  float e = __expf(2.f * x);
  return 1.f - 2.f * __builtin_amdgcn_rcpf(e + 1.f);
}
__device__ __forceinline__ v2f vlo(float4 v) { return (v2f){v.x, v.y}; }
__device__ __forceinline__ v2f vhi(float4 v) { return (v2f){v.z, v.w}; }

__global__ void prep_rot_kernel(const float* __restrict__ qw, float* __restrict__ U) {
  int t = threadIdx.x;
  if (t < 24) {
    float phi = qw[t*3+0], theta = qw[t*3+1], omega = qw[t*3+2];
    float st, ct; sincosf(0.5f*theta, &st, &ct);
    float sa, ca; sincosf(0.5f*(phi+omega), &sa, &ca);
    float sd, cd; sincosf(0.5f*(phi-omega), &sd, &cd);
    float4 o; o.x = ct*ca; o.y = -ct*sa; o.z = -st*cd; o.w = -st*sd;
    ((float4*)U)[t] = o;
  }
}

__global__ __launch_bounds__(64*WPB, 4) void qblock_kernel(
    const float* __restrict__ x,  const float* __restrict__ W1, const float* __restrict__ b1,
    const float* __restrict__ W2, const float* __restrict__ b2,
    const float* __restrict__ W3, const float* __restrict__ b3,
    const float* __restrict__ Urot, const float* __restrict__ Wp, const float* __restrict__ bp,
    float* __restrict__ out, int B4)
{
  __shared__ v2f    W1t[40 * 64];     // (k-pair, row): W1 transposed, 20 KB
  __shared__ v2f    W2t[32 * 32];     // 8 KB
  __shared__ float  h1s[WPB][NE][64];
  __shared__ float  h2s[WPB][NE][32];
  __shared__ v2f    cs [WPB][NE][16];
  __shared__ float4 csW[WPB][NE][8];

  const int tid  = threadIdx.x;
  const int lane = tid & 63;
  const int wv   = tid >> 6;
  int bw = blockIdx.x * WPB + wv;
  if (bw >= B4) bw = B4 - 1;
  bw = __builtin_amdgcn_readfirstlane(bw);
  const int e0 = NE * bw;
  const v2f* Ug2 = (const v2f*)Urot;

  // ---- stage W1, W2 transposed into LDS (coalesced reads) ----
  {
    const v2f* W1f2 = (const v2f*)W1;   // 2560 float2s, row-major [64][40]
    #pragma unroll
    for (int i = 0; i < 10; ++i) {
      int j = i * 256 + tid;            // j = r*40 + kk
      int r = j / 40, kk = j - r * 40;
      W1t[kk * 64 + r] = W1f2[j];
    }
    const v2f* W2f2 = (const v2f*)W2;   // 1024 float2s, [32][32]
    #pragma unroll
    for (int i = 0; i < 4; ++i) {
      int j = i * 256 + tid;
      int r = j >> 5, kk = j & 31;
      W2t[kk * 32 + r] = W2f2[j];
    }
  }
  __syncthreads();

  // ---- MLP layer 1: 80 -> 64 for 4 elements; W from LDS, x via s_load ----
  {
    const v2f* xA = (const v2f*)(x + (size_t)(e0 + 0) * 80);  // uniform
    const v2f* xB = (const v2f*)(x + (size_t)(e0 + 1) * 80);
    const v2f* xC = (const v2f*)(x + (size_t)(e0 + 2) * 80);
    const v2f* xD = (const v2f*)(x + (size_t)(e0 + 3) * 80);
    float bv = b1[lane];
    v2f aA = (v2f){bv, 0.f}, aB = aA, aC = aA, aD = aA;
    #pragma unroll 8
    for (int kk = 0; kk < 40; ++kk) {
      v2f w = W1t[kk * 64 + lane];
      pkfma_ip(w, xA[kk], aA);
      pkfma_ip(w, xB[kk], aB);
      pkfma_ip(w, xC[kk], aC);
      pkfma_ip(w, xD[kk], aD);
    }
    h1s[wv][0][lane] = fast_tanh(aA.x + aA.y);
    h1s[wv][1][lane] = fast_tanh(aB.x + aB.y);
    h1s[wv][2][lane] = fast_tanh(aC.x + aC.y);
    h1s[wv][3][lane] = fast_tanh(aD.x + aD.y);
  }
  __threadfence_block();

  // ---- layer 2: 64 -> 32; 2 elems per lane; W from LDS ----
  {
    const int ep = lane >> 5, row = lane & 31;
    const v2f* hA = (const v2f*)(&h1s[wv][2*ep+0][0]);
    const v2f* hB = (const v2f*)(&h1s[wv][2*ep+1][0]);
    float bv = b2[row];
    v2f aA = (v2f){bv, 0.f}, aB = aA;
    #pragma unroll 8
    for (int kk = 0; kk < 32; ++kk) {
      v2f w = W2t[kk * 32 + row];
      pkfma_ip(w, hA[kk], aA);
      pkfma_ip(w, hB[kk], aB);
    }
    h2s[wv][2*ep+0][row] = fast_tanh(aA.x + aA.y);
    h2s[wv][2*ep+1][row] = fast_tanh(aB.x + aB.y);
  }
  __threadfence_block();

  // ---- layer 3: 32 -> 16 angles; all 64 lanes (W3 global, L1-hot) ----
  {
    const int e = lane >> 4, row = lane & 15;
    const float4* hv = (const float4*)(&h2s[wv][e][0]);
    const float4* wr = (const float4*)(W3 + row * 32);
    v2f ac0 = (v2f){b3[row], 0.f}, ac1 = (v2f){0.f, 0.f};
    #pragma unroll
    for (int k = 0; k < 8; ++k) {
      float4 hk = hv[k], wk = wr[k];
      pkfma_ip(vlo(hk), vlo(wk), ac0);
      pkfma_ip(vhi(hk), vhi(wk), ac1);
    }
    float sh, ch; __sincosf(0.5f * ((ac0.x + ac0.y) + (ac1.x + ac1.y)), &sh, &ch);
    cs[wv][e][row] = (v2f){ch, sh};
  }
  __threadfence_block();

  // ---- combine W_i = Rot_l0_i . (RZ_i . RY_i): lane = (elem, wire) ----
  if (lane < 32) {
    const int e = lane >> 3, k = lane & 7;
    v2f yy = cs[wv][e][k], zz = cs[wv][e][k + 8];
    v2f u1 = (v2f){  yy.x * zz.x, -yy.x * zz.y };
    v2f u2 = (v2f){ -yy.y * zz.x,  yy.y * zz.y };
    v2f cu1 = (v2f){ u1.x, -u1.y };
    v2f cu2 = (v2f){ u2.x, -u2.y };
    v2f r1 = Ug2[2 * k], r2 = Ug2[2 * k + 1];
    v2f P1c = cmul(r1, u1);
    pkfma_bl_n(r2, cu2, P1c);
    pkfma_bh_mi(r2, cu2, P1c);
    v2f P2c = cmul(r1, u2);
    pkfma_bl(r2, cu1, P2c);
    pkfma_bh_i(r2, cu1, P2c);
    csW[wv][e][k] = make_float4(P1c.x, P1c.y, P2c.x, P2c.y);
  }
  __threadfence_block();

  // ---- per-lane constants ----
  const int a32 = (lane ^ 32) << 2;
  const int sb[6] = { (lane&32)<<26, (lane&16)<<27, (lane&8)<<28,
                      (lane&4)<<29, (lane&2)<<30, (lane&1)<<31 };
  const int addrA = ((lane ^ (lane >> 1)) & 63) << 2;
  const int addrB = addrA ^ 128;

  // ---- 4 states in 16 NAMED regs ----
  v2f sA0, sA1, sA2, sA3, sB0, sB1, sB2, sB3;
  v2f sC0, sC1, sC2, sC3, sD0, sD1, sD2, sD3;
  build_state(sA0, sA1, sA2, sA3, &csW[wv][0][0], lane);
  build_state(sB0, sB1, sB2, sB3, &csW[wv][1][0], lane);
  build_state(sC0, sC1, sC2, sC3, &csW[wv][2][0], lane);
  build_state(sD0, sD1, sD2, sD3, &csW[wv][3][0], lane);

  // interleaved CNOT ring: all 16 bpermutes issued back-to-back, then selects
  #define RING_ALL { \
    v2f t; \
    t = sA2; sA2 = sA3; sA3 = t;  t = sB2; sB2 = sB3; sB3 = t; \
    t = sC2; sC2 = sC3; sC3 = t;  t = sD2; sD2 = sD3; sD3 = t; \
    v2f qA0 = bperm2(addrA, sA0), qA2 = bperm2(addrA, sA2), \
        qA1 = bperm2(addrB, sA1), qA3 = bperm2(addrB, sA3), \
        qB0 = bperm2(addrA, sB0), qB2 = bperm2(addrA, sB2), \
        qB1 = bperm2(addrB, sB1), qB3 = bperm2(addrB, sB3), \
        qC0 = bperm2(addrA, sC0), qC2 = bperm2(addrA, sC2), \
        qC1 = bperm2(addrB, sC1), qC3 = bperm2(addrB, sC3), \
        qD0 = bperm2(addrA, sD0), qD2 = bperm2(addrA, sD2), \
        qD1 = bperm2(addrB, sD1), qD3 = bperm2(addrB, sD3); \
    bool c0 = (lane & 1) != 0; \
    sA0 = c0 ? qA2 : qA0; sA2 = c0 ? qA0 : qA2; \
    sA1 = c0 ? qA3 : qA1; sA3 = c0 ? qA1 : qA3; \
    sB0 = c0 ? qB2 : qB0; sB2 = c0 ? qB0 : qB2; \
    sB1 = c0 ? qB3 : qB1; sB3 = c0 ? qB1 : qB3; \
    sC0 = c0 ? qC2 : qC0; sC2 = c0 ? qC0 : qC2; \
    sC1 = c0 ? qC3 : qC1; sC3 = c0 ? qC1 : qC3; \
    sD0 = c0 ? qD2 : qD0; sD2 = c0 ? qD0 : qD2; \
    sD1 = c0 ? qD3 : qD1; sD3 = c0 ? qD1 : qD3; }
  RING_ALL

  #define LG01(l, i) { \
    v2f P1 = Ug2[((l)*8+(i))*2], P2 = Ug2[((l)*8+(i))*2+1]; \
    if constexpr ((i) == 0) { \
      gpair(sA0, sA2, P1, P2); gpair(sA1, sA3, P1, P2); \
      gpair(sB0, sB2, P1, P2); gpair(sB1, sB3, P1, P2); \
      gpair(sC0, sC2, P1, P2); gpair(sC1, sC3, P1, P2); \
      gpair(sD0, sD2, P1, P2); gpair(sD1, sD3, P1, P2); \
    } else { \
      gpair(sA0, sA1, P1, P2); gpair(sA2, sA3, P1, P2); \
      gpair(sB0, sB1, P1, P2); gpair(sB2, sB3, P1, P2); \
      gpair(sC0, sC1, P1, P2); gpair(sC2, sC3, P1, P2); \
      gpair(sD0, sD1, P1, P2); gpair(sD2, sD3, P1, P2); } }

  #define LGX(l, i) { \
    v2f P1 = Ug2[((l)*8+(i))*2], P2 = Ug2[((l)*8+(i))*2+1]; \
    P1.y = xorf(P1.y, sb[(i)-2]); P2.x = xorf(P2.x, sb[(i)-2]); \
    v2f pA0 = xch2<(1<<(7-(i)))>(sA0, a32), pA1 = xch2<(1<<(7-(i)))>(sA1, a32), \
        pA2 = xch2<(1<<(7-(i)))>(sA2, a32), pA3 = xch2<(1<<(7-(i)))>(sA3, a32), \
        pB0 = xch2<(1<<(7-(i)))>(sB0, a32), pB1 = xch2<(1<<(7-(i)))>(sB1, a32), \
        pB2 = xch2<(1<<(7-(i)))>(sB2, a32), pB3 = xch2<(1<<(7-(i)))>(sB3, a32), \
        pC0 = xch2<(1<<(7-(i)))>(sC0, a32), pC1 = xch2<(1<<(7-(i)))>(sC1, a32), \
        pC2 = xch2<(1<<(7-(i)))>(sC2, a32), pC3 = xch2<(1<<(7-(i)))>(sC3, a32), \
        pD0 = xch2<(1<<(7-(i)))>(sD0, a32), pD1 = xch2<(1<<(7-(i)))>(sD1, a32), \
        pD2 = xch2<(1<<(7-(i)))>(sD2, a32), pD3 = xch2<(1<<(7-(i)))>(sD3, a32); \
    sA0 = glane(sA0, pA0, P1, P2); sA1 = glane(sA1, pA1, P1, P2); \
    sA2 = glane(sA2, pA2, P1, P2); sA3 = glane(sA3, pA3, P1, P2); \
    sB0 = glane(sB0, pB0, P1, P2); sB1 = glane(sB1, pB1, P1, P2); \
    sB2 = glane(sB2, pB2, P1, P2); sB3 = glane(sB3, pB3, P1, P2); \
    sC0 = glane(sC0, pC0, P1, P2); sC1 = glane(sC1, pC1, P1, P2); \
    sC2 = glane(sC2, pC2, P1, P2); sC3 = glane(sC3, pC3, P1, P2); \
    sD0 = glane(sD0, pD0, P1, P2); sD1 = glane(sD1, pD1, P1, P2); \
    sD2 = glane(sD2, pD2, P1, P2); sD3 = glane(sD3, pD3, P1, P2); }

  LG01(1,0) LG01(1,1) LGX(1,2) LGX(1,3) LGX(1,4) LGX(1,5) LGX(1,6) LGX(1,7)
  RING_ALL
  LG01(2,0) LG01(2,1) LGX(2,2) LGX(2,3) LGX(2,4) LGX(2,5) LGX(2,6) LGX(2,7)
  #undef LG01
  #undef LGX
  #undef RING_ALL

  // ---- interleaved readout for 4 elements (pair-groups u=(A,B), w=(C,D)) ----
  v2f zu0,zu1,zu2,zu3,zu4,zu5,zu6,zu7;
  v2f zw0,zw1,zw2,zw3,zw4,zw5,zw6,zw7;
  {
    v2f pu0 = (v2f){fmaf(sA0.x,sA0.x,sA0.y*sA0.y), fmaf(sB0.x,sB0.x,sB0.y*sB0.y)};
    v2f pu1 = (v2f){fmaf(sA1.x,sA1.x,sA1.y*sA1.y), fmaf(sB1.x,sB1.x,sB1.y*sB1.y)};
    v2f pu2 = (v2f){fmaf(sA2.x,sA2.x,sA2.y*sA2.y), fmaf(sB2.x,sB2.x,sB2.y*sB2.y)};
    v2f pu3 = (v2f){fmaf(sA3.x,sA3.x,sA3.y*sA3.y), fmaf(sB3.x,sB3.x,sB3.y*sB3.y)};
    v2f pw0 = (v2f){fmaf(sC0.x,sC0.x,sC0.y*sC0.y), fmaf(sD0.x,sD0.x,sD0.y*sD0.y)};
    v2f pw1 = (v2f){fmaf(sC1.x,sC1.x,sC1.y*sC1.y), fmaf(sD1.x,sD1.x,sD1.y*sD1.y)};
    v2f pw2 = (v2f){fmaf(sC2.x,sC2.x,sC2.y*sC2.y), fmaf(sD2.x,sD2.x,sD2.y*sD2.y)};
    v2f pw3 = (v2f){fmaf(sC3.x,sC3.x,sC3.y*sC3.y), fmaf(sD3.x,sD3.x,sD3.y*sD3.y)};
    v2f Eu = (pu0 + pu3) - (pu1 + pu2), Fu = (pu0 + pu2) - (pu1 + pu3);
    v2f Ew = (pw0 + pw3) - (pw1 + pw2), Fw = (pw0 + pw2) - (pw1 + pw3);
    const int pl = (__popc(lane) & 1) << 31;
    v2f Fvu = xor2(Fu, pl), Fvw = xor2(Fw, pl);
    v2f Smu = Eu, Smw = Ew;
    v2f d1u, d2u, d3u, d4u, d5u, d6u, d1w, d2w, d3w, d4w, d5w, d6w;
    { v2f pu = xch2<32>(Smu, a32); v2f pw = xch2<32>(Smw, a32);
      d1u = xor2(Smu - pu, sb[0]); Smu += pu;
      d1w = xor2(Smw - pw, sb[0]); Smw += pw; }
    { v2f pu = xch2<16>(Smu, a32), qu = xch2<16>(d1u, a32);
      v2f pw = xch2<16>(Smw, a32), qw = xch2<16>(d1w, a32);
      Smu += pu; d2u = xor2(d1u - qu, sb[1]); d1u += qu;
      Smw += pw; d2w = xor2(d1w - qw, sb[1]); d1w += qw; }
    { v2f pu = xch2<8>(Smu, a32), qu = xch2<8>(d1u, a32), ru = xch2<8>(d2u, a32);
      v2f pw = xch2<8>(Smw, a32), qw = xch2<8>(d1w, a32), rw = xch2<8>(d2w, a32);
      Smu += pu; d1u += qu; d3u = xor2(d2u - ru, sb[2]); d2u += ru;
      Smw += pw; d1w += qw; d3w = xor2(d2w - rw, sb[2]); d2w += rw; }
    { v2f pu = xch2<4>(Smu, a32), qu = xch2<4>(d1u, a32),
          ru = xch2<4>(d2u, a32), tu = xch2<4>(d3u, a32);
      v2f pw = xch2<4>(Smw, a32), qw = xch2<4>(d1w, a32),
          rw = xch2<4>(d2w, a32), tw = xch2<4>(d3w, a32);
      Smu += pu; d1u += qu; d2u += ru; d4u = xor2(d3u - tu, sb[3]); d3u += tu;
      Smw += pw; d1w += qw; d2w += rw; d4w = xor2(d3w - tw, sb[3]); d3w += tw; }
    { v2f pu = xch2<2>(Smu, a32), qu = xch2<2>(d1u, a32), ru = xch2<2>(d2u, a32),
          tu = xch2<2>(d3u, a32), wu = xch2<2>(d4u, a32);
      v2f pw = xch2<2>(Smw, a32), qw = xch2<2>(d1w, a32), rw = xch2<2>(d2w, a32),
          tw = xch2<2>(d3w, a32), ww = xch2<2>(d4w, a32);
      Smu += pu; d1u += qu; d2u += ru; d3u += tu;
      d5u = xor2(d4u - wu, sb[4]); d4u += wu;
      Smw += pw; d1w += qw; d2w += rw; d3w += tw;
      d5w = xor2(d4w - ww, sb[4]); d4w += ww; }
    { v2f pu = xch2<1>(Smu, a32), qu = xch2<1>(d1u, a32), ru = xch2<1>(d2u, a32),
          tu = xch2<1>(d3u, a32), wu = xch2<1>(d4u, a32), vu = xch2<1>(d5u, a32);
      v2f pw = xch2<1>(Smw, a32), qw = xch2<1>(d1w, a32), rw = xch2<1>(d2w, a32),
          tw = xch2<1>(d3w, a32), ww = xch2<1>(d4w, a32), vw = xch2<1>(d5w, a32);
      Smu += pu; d1u += qu; d2u += ru; d3u += tu; d4u += wu;
      d6u = xor2(d5u - vu, sb[5]); d5u += vu;
      Smw += pw; d1w += qw; d2w += rw; d3w += tw; d4w += ww;
      d6w = xor2(d5w - vw, sb[5]); d5w += vw; }
    Fvu += xch2<32>(Fvu, a32); Fvw += xch2<32>(Fvw, a32);
    Fvu += xch2<16>(Fvu, a32); Fvw += xch2<16>(Fvw, a32);
    Fvu += xch2<8>(Fvu, a32);  Fvw += xch2<8>(Fvw, a32);
    Fvu += xch2<4>(Fvu, a32);  Fvw += xch2<4>(Fvw, a32);
    Fvu += xch2<2>(Fvu, a32);  Fvw += xch2<2>(Fvw, a32);
    Fvu += xch2<1>(Fvu, a32);  Fvw += xch2<1>(Fvw, a32);
    zu0 = Fvu; zu1 = Smu; zu2 = d1u; zu3 = d2u;
    zu4 = d3u; zu5 = d4u; zu6 = d5u; zu7 = d6u;
    zw0 = Fvw; zw1 = Smw; zw2 = d1w; zw3 = d2w;
    zw4 = d3w; zw5 = d4w; zw6 = d5w; zw7 = d6w;
  }

  // ---- packed projection + stores ----
  const int r0 = 2 * lane;
  const float4* wp = (const float4*)(Wp + r0 * 8);
  float4 w0v = wp[0], w1v = wp[1], w2v = wp[2], w3v = wp[3];
  float2 bpv = ((const float2*)bp)[lane];
  #define PROJ_STORE(P, eA, eB) { \
    v2f o0 = (v2f){bpv.x, bpv.x}; \
    v2f o1 = (v2f){bpv.y, bpv.y}; \
    o0 += z##P##0*w0v.x + z##P##1*w0v.y + z##P##2*w0v.z + z##P##3*w0v.w \
        + z##P##4*w1v.x + z##P##5*w1v.y + z##P##6*w1v.z + z##P##7*w1v.w; \
    o1 += z##P##0*w2v.x + z##P##1*w2v.y + z##P##2*w2v.z + z##P##3*w2v.w \
        + z##P##4*w3v.x + z##P##5*w3v.y + z##P##6*w3v.z + z##P##7*w3v.w; \
    ((float2*)(out + (size_t)(e0 + (eA)) * 128))[lane] = make_float2(o0.x, o1.x); \
    ((float2*)(out + (size_t)(e0 + (eB)) * 128))[lane] = make_float2(o0.y, o1.y); }
  PROJ_STORE(u, 0, 1)
  PROJ_STORE(w, 2, 3)
  #undef PROJ_STORE
}

extern "C" void kernel_launch(void* const* d_in, const int* in_sizes, int n_in,
                              void* d_out, int out_size, void* d_ws, size_t ws_size,
                              hipStream_t stream) {
  const float* x  = (const float*)d_in[0];
  const float* W1 = (const float*)d_in[1];
  const float* b1 = (const float*)d_in[2];
  const float* W2 = (const float*)d_in[3];
  const float* b2 = (const float*)d_in[4];
  const float* W3 = (const float*)d_in[5];
  const float* b3 = (const float*)d_in[6];
  const float* qw = (const float*)d_in[7];
  const float* Wp = (const float*)d_in[8];
  const float* bp = (const float*)d_in[9];
  float* out = (float*)d_out;
  float* Urot = (float*)d_ws;

  const int B = in_sizes[0] / 80;
  const int B4 = B / NE;
  prep_rot_kernel<<<1, 64, 0, stream>>>(qw, Urot);
  const int grid = (B4 + WPB - 1) / WPB;
  qblock_kernel<<<grid, 64 * WPB, 0, stream>>>(x, W1, b1, W2, b2, W3, b3,
                                               Urot, Wp, bp, out, B4);
}